// Round 6
// baseline (459.264 us; speedup 1.0000x reference)
//
#include <hip/hip_runtime.h>

#define N_NODES 100000
#define N_EDGES 1600000
#define DIM 128

#define BSHIFT 5
#define BNODES 32                                 // nodes per bucket
#define NBUCK ((N_NODES + BNODES - 1) / BNODES)   // 3125
#define NSUB 8                                    // one sub-bucket per XCD (blockIdx & 7)
#define SUBCAP 128                                // mean 64 -> 8-sigma headroom

typedef unsigned int uint;

// ---------------- CSR build (bucketed, XCD-local sub-buckets) ----------------

__global__ __launch_bounds__(256) void k_init_bcur(int* __restrict__ bcur) {
  int i = blockIdx.x * 256 + threadIdx.x;
  if (i < NBUCK * NSUB) bcur[i] = i * SUBCAP;
}

__global__ __launch_bounds__(256) void k_bucket(const int* __restrict__ ei, int* __restrict__ bcur,
                                                uint* __restrict__ stage) {
  int e = blockIdx.x * 256 + threadIdx.x;
  int sub = blockIdx.x & (NSUB - 1);
  if (e < N_EDGES) {
    int s = ei[e];
    int d = ei[N_EDGES + e];
    int b = d >> BSHIFT;
    int idx = sub * NBUCK + b;        // XCD-contiguous cursor + stage layout
    int pos = atomicAdd(&bcur[idx], 1);
    if (pos < (idx + 1) * SUBCAP)     // overflow guard (statistically unreachable)
      stage[pos] = (uint)s | ((uint)(d & (BNODES - 1)) << 17);
  }
}

__global__ __launch_bounds__(256) void k_bcount(const int* __restrict__ bcur, const uint* __restrict__ stage,
                                                int* __restrict__ deg, float* __restrict__ dinv) {
  __shared__ int cnt[BNODES];
  int b = blockIdx.x;
  int t = threadIdx.x;
  if (t < BNODES) cnt[t] = 0;
  __syncthreads();
  for (int s = 0; s < NSUB; ++s) {
    int idx = s * NBUCK + b;
    int base = idx * SUBCAP;
    int n = bcur[idx] - base;
    if (n > SUBCAP) n = SUBCAP;
    for (int i = t; i < n; i += 256) {
      uint u = stage[base + i];
      atomicAdd(&cnt[u >> 17], 1);
    }
  }
  __syncthreads();
  if (t < BNODES) {
    int node = b * BNODES + t;
    int c = cnt[t];
    deg[node] = c;
    dinv[node] = rsqrtf((float)(c + 1));  // +1 self-loop; always > 0
  }
}

__global__ __launch_bounds__(256) void k_scan_blocks(const int* __restrict__ deg, int* __restrict__ bsum) {
  __shared__ int sd[256];
  int t = threadIdx.x;
  int base = blockIdx.x * 1024 + t * 4;
  int s = 0;
#pragma unroll
  for (int j = 0; j < 4; ++j) {
    int i = base + j;
    if (i < N_NODES) s += deg[i];
  }
  sd[t] = s;
  __syncthreads();
  for (int off = 128; off > 0; off >>= 1) {
    if (t < off) sd[t] += sd[t + off];
    __syncthreads();
  }
  if (t == 0) bsum[blockIdx.x] = sd[0];
}

__global__ void k_scan_top(int* __restrict__ bsum, int nb, int* __restrict__ rowptr) {
  int run = 0;
  for (int i = 0; i < nb; ++i) {
    int v = bsum[i];
    bsum[i] = run;
    run += v;
  }
  rowptr[N_NODES] = run;
}

__global__ __launch_bounds__(256) void k_scan_final(const int* __restrict__ deg, const int* __restrict__ bsum,
                                                    int* __restrict__ rowptr) {
  __shared__ int sd[256];
  int t = threadIdx.x;
  int base = blockIdx.x * 1024 + t * 4;
  int v[4];
  int s = 0;
#pragma unroll
  for (int j = 0; j < 4; ++j) {
    int i = base + j;
    v[j] = (i < N_NODES) ? deg[i] : 0;
    s += v[j];
  }
  sd[t] = s;
  __syncthreads();
  for (int off = 1; off < 256; off <<= 1) {
    int a = (t >= off) ? sd[t - off] : 0;
    __syncthreads();
    sd[t] += a;
    __syncthreads();
  }
  int run = bsum[blockIdx.x] + sd[t] - s;
#pragma unroll
  for (int j = 0; j < 4; ++j) {
    int i = base + j;
    if (i < N_NODES) {
      rowptr[i] = run;
      run += v[j];
    }
  }
}

// Phase B2: per-bucket scatter into the bucket's contiguous CSR range. src only (4 B).
__global__ __launch_bounds__(256) void k_scatter_final(const int* __restrict__ bcur, const uint* __restrict__ stage,
                                                       const int* __restrict__ rowptr,
                                                       int* __restrict__ es) {
  __shared__ int cur[BNODES];
  int b = blockIdx.x;
  int t = threadIdx.x;
  if (t < BNODES) cur[t] = rowptr[b * BNODES + t];
  __syncthreads();
  for (int s = 0; s < NSUB; ++s) {
    int idx = s * NBUCK + b;
    int base = idx * SUBCAP;
    int n = bcur[idx] - base;
    if (n > SUBCAP) n = SUBCAP;
    for (int i = t; i < n; i += 256) {
      uint u = stage[base + i];
      int src = (int)(u & 0x1FFFFu);
      int dl = (int)(u >> 17);
      int pos = atomicAdd(&cur[dl], 1);
      es[pos] = src;
    }
  }
}

// ---------------- GEMM: OutB[nrows,128](bf16) = X[nrows,128] @ W[128,128] ----------------

__device__ __forceinline__ void fma4(float* a, float xk, const float4& q) {
  a[0] += xk * q.x;
  a[1] += xk * q.y;
  a[2] += xk * q.z;
  a[3] += xk * q.w;
}

__device__ __forceinline__ uint bf16_rtne(float f) {
  uint u = __float_as_uint(f);
  return (u + 0x7fffu + ((u >> 16) & 1u)) >> 16;
}

__global__ __launch_bounds__(256) void k_gemm(const float* __restrict__ X, const float* __restrict__ W,
                                              uint* __restrict__ OutB, int nrows) {
  __shared__ float xs[64 * 32];   // 8 KB
  __shared__ float ws[32 * 128];  // 16 KB
  const int tid = threadIdx.x;
  const int R = blockIdx.x * 64;
  const int tcol = (tid & 31) * 4;   // 0..124
  const int trow = (tid >> 5) * 8;   // 0..56
  float acc[8][4] = {};

  for (int kc = 0; kc < DIM; kc += 32) {
    const float* wsrc = W + kc * DIM;
#pragma unroll
    for (int v = 0; v < 4; ++v) {
      int idx = tid + v * 256;
      *(float4*)(ws + idx * 4) = *(const float4*)(wsrc + idx * 4);
    }
#pragma unroll
    for (int v = 0; v < 2; ++v) {
      int slot = tid + v * 256;
      int row = slot >> 3;
      int off = (slot & 7) * 4;
      int gr = R + row;
      if (gr >= nrows) gr = nrows - 1;
      *(float4*)(xs + row * 32 + off) = *(const float4*)(X + (size_t)gr * DIM + kc + off);
    }
    __syncthreads();
#pragma unroll
    for (int kk = 0; kk < 32; kk += 4) {
      float4 xv[8];
      float4 wv[4];
#pragma unroll
      for (int i = 0; i < 8; ++i) xv[i] = *(const float4*)(xs + (trow + i) * 32 + kk);
#pragma unroll
      for (int j = 0; j < 4; ++j) wv[j] = *(const float4*)(ws + (kk + j) * DIM + tcol);
#pragma unroll
      for (int i = 0; i < 8; ++i) {
        fma4(acc[i], xv[i].x, wv[0]);
        fma4(acc[i], xv[i].y, wv[1]);
        fma4(acc[i], xv[i].z, wv[2]);
        fma4(acc[i], xv[i].w, wv[3]);
      }
    }
    __syncthreads();
  }
#pragma unroll
  for (int i = 0; i < 8; ++i) {
    int gr = R + trow + i;
    if (gr < nrows) {
      uint2 o;
      o.x = bf16_rtne(acc[i][0]) | (bf16_rtne(acc[i][1]) << 16);
      o.y = bf16_rtne(acc[i][2]) | (bf16_rtne(acc[i][3]) << 16);
      *(uint2*)(OutB + (size_t)gr * 64 + (tcol >> 1)) = o;
    }
  }
}

// ---------------- Aggregation: one wave per node, 8 rows in flight ----------------

__device__ __forceinline__ void bacc(float& ax, float& ay, uint v, float w) {
  ax += w * __uint_as_float(v << 16);
  ay += w * __uint_as_float(v & 0xffff0000u);
}

__global__ __launch_bounds__(256) void k_agg(const uint* __restrict__ hb, const float* __restrict__ dinv,
                                             const int* __restrict__ rowptr, const int* __restrict__ es,
                                             const float* __restrict__ bias, float* __restrict__ out) {
  int wid = threadIdx.x >> 6;
  int lane = threadIdx.x & 63;
  int node = blockIdx.x * 4 + wid;
  if (node >= N_NODES) return;
  int beg = rowptr[node];
  int end = rowptr[node + 1];
  float dn = dinv[node];
  uint selfv = hb[(size_t)node * 64 + lane];
  float ax = 0.f, ay = 0.f;
  bacc(ax, ay, selfv, dn);

  int e = beg;
  for (; e + 8 <= end; e += 8) {
    int s0 = es[e + 0];
    int s1 = es[e + 1];
    int s2 = es[e + 2];
    int s3 = es[e + 3];
    int s4 = es[e + 4];
    int s5 = es[e + 5];
    int s6 = es[e + 6];
    int s7 = es[e + 7];
    // dinv gathers hit the L2-resident 400 KB table; row gathers go to L3.
    // All 16 loads independent -> 8 rows in flight.
    float d0 = dinv[s0], d1 = dinv[s1], d2 = dinv[s2], d3 = dinv[s3];
    float d4 = dinv[s4], d5 = dinv[s5], d6 = dinv[s6], d7 = dinv[s7];
    uint v0 = hb[(size_t)s0 * 64 + lane];
    uint v1 = hb[(size_t)s1 * 64 + lane];
    uint v2 = hb[(size_t)s2 * 64 + lane];
    uint v3 = hb[(size_t)s3 * 64 + lane];
    uint v4 = hb[(size_t)s4 * 64 + lane];
    uint v5 = hb[(size_t)s5 * 64 + lane];
    uint v6 = hb[(size_t)s6 * 64 + lane];
    uint v7 = hb[(size_t)s7 * 64 + lane];
    bacc(ax, ay, v0, d0);
    bacc(ax, ay, v1, d1);
    bacc(ax, ay, v2, d2);
    bacc(ax, ay, v3, d3);
    bacc(ax, ay, v4, d4);
    bacc(ax, ay, v5, d5);
    bacc(ax, ay, v6, d6);
    bacc(ax, ay, v7, d7);
  }
  for (; e < end; ++e) {
    int s = es[e];
    float ds = dinv[s];
    uint v = hb[(size_t)s * 64 + lane];
    bacc(ax, ay, v, ds);
  }

  int c = lane * 2;
  float2 bv = *(const float2*)(bias + c);
  float2 o;
  o.x = dn * ax + bv.x;
  o.y = dn * ay + bv.y;
  *(float2*)(out + (size_t)node * DIM + c) = o;
}

// ---------------- launch ----------------

extern "C" void kernel_launch(void* const* d_in, const int* in_sizes, int n_in,
                              void* d_out, int out_size, void* d_ws, size_t ws_size,
                              hipStream_t stream) {
  const float* x  = (const float*)d_in[0];
  const int*   ei = (const int*)d_in[1];   // int32: [0..E)=src, [E..2E)=dst
  const float* W1 = (const float*)d_in[2];
  const float* b1 = (const float*)d_in[3];
  const float* W2 = (const float*)d_in[4];
  const float* b2 = (const float*)d_in[5];
  float* out = (float*)d_out;

  char* p = (char*)d_ws;
  uint*  hb     = (uint*)p;   p += (size_t)N_NODES * 64 * sizeof(uint);          // 25.6 MB
  int*   es     = (int*)p;    p += (size_t)N_EDGES * sizeof(int);                // 6.4 MB
  uint*  stage  = (uint*)p;   p += (size_t)NBUCK * NSUB * SUBCAP * sizeof(uint); // 12.8 MB
  int*   deg    = (int*)p;    p += (size_t)N_NODES * sizeof(int);
  int*   rowptr = (int*)p;    p += (size_t)(N_NODES + 1) * sizeof(int);
  int*   bcur   = (int*)p;    p += (size_t)NBUCK * NSUB * sizeof(int);
  float* dinv   = (float*)p;  p += (size_t)N_NODES * sizeof(float);
  int*   bsum   = (int*)p;    // 98 ints

  const int NB = (N_NODES + 1023) / 1024;  // 98

  k_init_bcur<<<(NBUCK * NSUB + 255) / 256, 256, 0, stream>>>(bcur);
  k_bucket<<<(N_EDGES + 255) / 256, 256, 0, stream>>>(ei, bcur, stage);
  k_bcount<<<NBUCK, 256, 0, stream>>>(bcur, stage, deg, dinv);
  k_scan_blocks<<<NB, 256, 0, stream>>>(deg, bsum);
  k_scan_top<<<1, 1, 0, stream>>>(bsum, NB, rowptr);
  k_scan_final<<<NB, 256, 0, stream>>>(deg, bsum, rowptr);
  k_scatter_final<<<NBUCK, 256, 0, stream>>>(bcur, stage, rowptr, es);

  // layer 1
  k_gemm<<<(N_NODES + 63) / 64, 256, 0, stream>>>(x, W1, hb, N_NODES);
  k_agg<<<(N_NODES + 3) / 4, 256, 0, stream>>>(hb, dinv, rowptr, es, b1, out);
  // layer 2
  k_gemm<<<(N_NODES + 63) / 64, 256, 0, stream>>>(out, W2, hb, N_NODES);
  k_agg<<<(N_NODES + 3) / 4, 256, 0, stream>>>(hb, dinv, rowptr, es, b2, out);
}